// Round 4
// baseline (77.187 us; speedup 1.0000x reference)
//
#include <hip/hip_runtime.h>
#include <hip/hip_bf16.h>

// out[m, p*64+q] = sum_{k,l} x[m, k*64+l] * A[p,k] * B[q,l] + bias[p*64+q]
// Per row m: U = X * B^T (contract l), then out_tile^T = U^T * A^T (contract k)
// so each lane's 4 accumulator values are CONSECUTIVE q -> float4 stores.
// One wave per row, 8192 waves total. MFMA 16x16x32 bf16, fp32 accumulate.
// Round 3: non-temporal output stores so the 128 MiB write stream does not
// evict x from the 256 MiB Infinity Cache between graph replays.

typedef __bf16 bf16x8 __attribute__((ext_vector_type(8)));
typedef __bf16 bf16x4 __attribute__((ext_vector_type(4)));
typedef float  f32x4  __attribute__((ext_vector_type(4)));

#define MFMA16(Aop, Bop, C) __builtin_amdgcn_mfma_f32_16x16x32_bf16(Aop, Bop, C, 0, 0, 0)

__device__ __forceinline__ bf16x8 load_cvt8(const float* __restrict__ p) {
    const float4 a = *reinterpret_cast<const float4*>(p);
    const float4 b = *reinterpret_cast<const float4*>(p + 4);
    bf16x8 r;
    r[0] = (__bf16)a.x; r[1] = (__bf16)a.y; r[2] = (__bf16)a.z; r[3] = (__bf16)a.w;
    r[4] = (__bf16)b.x; r[5] = (__bf16)b.y; r[6] = (__bf16)b.z; r[7] = (__bf16)b.w;
    return r;
}

__global__ __launch_bounds__(256, 4)
void kron_linear_kernel(const float* __restrict__ x,
                        const float* __restrict__ A,
                        const float* __restrict__ B,
                        const float* __restrict__ bias,
                        float* __restrict__ out) {
    // Per-wave 64x64 bf16 U buffer, stored transposed (k-contiguous), XOR-swizzled.
    __shared__ __align__(16) __bf16 Ulds[4][64 * 64];

    const int lane = threadIdx.x & 63;
    const int wv   = threadIdx.x >> 6;    // wave in block, 0..3
    const int lr   = lane & 15;           // lane % 16
    const int hi   = lane >> 4;           // 0..3 (K-chunk group)
    const int m    = blockIdx.x * 4 + wv; // row id, 0..8191

    char* ubase = (char*)(&Ulds[wv][0]);
    const float* xrow = x + (size_t)m * 4096;

    // ---- Constant fragments ----
    // Af[t][kt]: lane holds A[16t+lr][32kt + 8hi + j]   (used as B-operand = A^T)
    // Bf[t][kt]: lane holds B[16t+lr][32kt + 8hi + j]   (stage-1 B-operand)
    bf16x8 Af[4][2], Bf[4][2];
    #pragma unroll
    for (int t = 0; t < 4; ++t) {
        #pragma unroll
        for (int kt = 0; kt < 2; ++kt) {
            const int row = 16 * t + lr;
            const int c0  = 32 * kt + 8 * hi;
            Af[t][kt] = load_cvt8(A + row * 64 + c0);
            Bf[t][kt] = load_cvt8(B + row * 64 + c0);
        }
    }

    // ---- X fragments: stage-1 A-operand. lane holds X[16mt+lr][32kt+8hi+j] ----
    bf16x8 Xf[4][2];
    #pragma unroll
    for (int mt = 0; mt < 4; ++mt) {
        #pragma unroll
        for (int kt = 0; kt < 2; ++kt) {
            Xf[mt][kt] = load_cvt8(xrow + (16 * mt + lr) * 64 + 32 * kt + 8 * hi);
        }
    }

    // ---- Stage 1: U(k,q) = sum_l X(k,l) * B(q,l); write U to LDS k-contiguous.
    // C/D layout: lane's r-th value is U[16mt + 4hi + r][16nt + lr].
    // Byte offset = q*128 + k*2, XOR-swizzled by ((q&7)<<4). ----
    #pragma unroll
    for (int mt = 0; mt < 4; ++mt) {
        #pragma unroll
        for (int nt = 0; nt < 4; ++nt) {
            f32x4 u = {0.f, 0.f, 0.f, 0.f};
            u = MFMA16(Xf[mt][0], Bf[nt][0], u);
            u = MFMA16(Xf[mt][1], Bf[nt][1], u);
            const int q   = 16 * nt + lr;
            const int k0  = 16 * mt + 4 * hi;
            const int off = (q * 128 + k0 * 2) ^ ((q & 7) << 4);
            bf16x4 v;
            v[0] = (__bf16)u[0];
            v[1] = (__bf16)u[1];
            v[2] = (__bf16)u[2];
            v[3] = (__bf16)u[3];
            *reinterpret_cast<bf16x4*>(ubase + off) = v;
        }
    }

    // Make this wave's LDS writes visible to its reads.
    asm volatile("s_waitcnt lgkmcnt(0)" ::: "memory");

    // ---- U^T fragments (stage-2 A-operand): lane holds U[32kt+8hi+j][16qt+lr],
    // i.e. Aop[row=q=lr][K=k] = U^T. One ds_read_b128 each, conflict-free. ----
    bf16x8 Uf[2][4];
    #pragma unroll
    for (int kt = 0; kt < 2; ++kt) {
        #pragma unroll
        for (int qt = 0; qt < 4; ++qt) {
            const int q   = 16 * qt + lr;
            const int k0  = 32 * kt + 8 * hi;
            const int off = (q * 128 + k0 * 2) ^ ((q & 7) << 4);
            Uf[kt][qt] = *reinterpret_cast<const bf16x8*>(ubase + off);
        }
    }

    // ---- Stage 2 (transposed): D[q][p] = sum_k U^T[q][k] * A^T[k][p].
    // Aop = Uf (row=q), Bop = Af (col=p). Lane's r-th value:
    // D[16qt + 4hi + r][16pt + lr] = out[p=16pt+lr][q=16qt+4hi+r]
    // -> 4 consecutive q values -> float4 non-temporal store. ----
    float* orow = out + (size_t)m * 4096;
    #pragma unroll
    for (int pt = 0; pt < 4; ++pt) {
        #pragma unroll
        for (int qt = 0; qt < 4; ++qt) {
            f32x4 acc = {0.f, 0.f, 0.f, 0.f};
            acc = MFMA16(Uf[0][qt], Af[pt][0], acc);
            acc = MFMA16(Uf[1][qt], Af[pt][1], acc);
            const int p   = 16 * pt + lr;
            const int q0  = 16 * qt + 4 * hi;
            const int col = p * 64 + q0;
            const f32x4 bv = *reinterpret_cast<const f32x4*>(bias + col);
            f32x4 o;
            o[0] = acc[0] + bv[0];
            o[1] = acc[1] + bv[1];
            o[2] = acc[2] + bv[2];
            o[3] = acc[3] + bv[3];
            __builtin_nontemporal_store(o, reinterpret_cast<f32x4*>(orow + col));
        }
    }
}

extern "C" void kernel_launch(void* const* d_in, const int* in_sizes, int n_in,
                              void* d_out, int out_size, void* d_ws, size_t ws_size,
                              hipStream_t stream) {
    const float* x    = (const float*)d_in[0];
    const float* A    = (const float*)d_in[1];
    const float* B    = (const float*)d_in[2];
    const float* bias = (const float*)d_in[3];
    float* out        = (float*)d_out;

    // 2048 blocks x 4 waves = 8192 waves, one output row each.
    kron_linear_kernel<<<dim3(2048), dim3(256), 0, stream>>>(x, A, B, bias, out);
}

// Round 5
// 77.123 us; speedup vs baseline: 1.0008x; 1.0008x over previous
//
#include <hip/hip_runtime.h>
#include <hip/hip_bf16.h>

// out[m, p*64+q] = sum_{k,l} x[m, k*64+l] * A[p,k] * B[q,l] + bias[p*64+q]
// Per row m: U = X * B^T (contract l), then out_tile^T = U^T * A^T (contract k)
// so each lane's 4 accumulator values are CONSECUTIVE q -> float4 stores.
// One wave per row, 8192 waves total. MFMA 16x16x32 bf16, fp32 accumulate.
// Round 3: non-temporal output stores so the 128 MiB write stream does not
// evict x from the 256 MiB Infinity Cache between graph replays.

typedef __bf16 bf16x8 __attribute__((ext_vector_type(8)));
typedef __bf16 bf16x4 __attribute__((ext_vector_type(4)));
typedef float  f32x4  __attribute__((ext_vector_type(4)));

#define MFMA16(Aop, Bop, C) __builtin_amdgcn_mfma_f32_16x16x32_bf16(Aop, Bop, C, 0, 0, 0)

__device__ __forceinline__ bf16x8 load_cvt8(const float* __restrict__ p) {
    const float4 a = *reinterpret_cast<const float4*>(p);
    const float4 b = *reinterpret_cast<const float4*>(p + 4);
    bf16x8 r;
    r[0] = (__bf16)a.x; r[1] = (__bf16)a.y; r[2] = (__bf16)a.z; r[3] = (__bf16)a.w;
    r[4] = (__bf16)b.x; r[5] = (__bf16)b.y; r[6] = (__bf16)b.z; r[7] = (__bf16)b.w;
    return r;
}

__global__ __launch_bounds__(256, 4)
void kron_linear_kernel(const float* __restrict__ x,
                        const float* __restrict__ A,
                        const float* __restrict__ B,
                        const float* __restrict__ bias,
                        float* __restrict__ out) {
    // Per-wave 64x64 bf16 U buffer, stored transposed (k-contiguous), XOR-swizzled.
    __shared__ __align__(16) __bf16 Ulds[4][64 * 64];

    const int lane = threadIdx.x & 63;
    const int wv   = threadIdx.x >> 6;    // wave in block, 0..3
    const int lr   = lane & 15;           // lane % 16
    const int hi   = lane >> 4;           // 0..3 (K-chunk group)
    const int m    = blockIdx.x * 4 + wv; // row id, 0..8191

    char* ubase = (char*)(&Ulds[wv][0]);
    const float* xrow = x + (size_t)m * 4096;

    // ---- Constant fragments ----
    // Af[t][kt]: lane holds A[16t+lr][32kt + 8hi + j]   (used as B-operand = A^T)
    // Bf[t][kt]: lane holds B[16t+lr][32kt + 8hi + j]   (stage-1 B-operand)
    bf16x8 Af[4][2], Bf[4][2];
    #pragma unroll
    for (int t = 0; t < 4; ++t) {
        #pragma unroll
        for (int kt = 0; kt < 2; ++kt) {
            const int row = 16 * t + lr;
            const int c0  = 32 * kt + 8 * hi;
            Af[t][kt] = load_cvt8(A + row * 64 + c0);
            Bf[t][kt] = load_cvt8(B + row * 64 + c0);
        }
    }

    // ---- X fragments: stage-1 A-operand. lane holds X[16mt+lr][32kt+8hi+j] ----
    bf16x8 Xf[4][2];
    #pragma unroll
    for (int mt = 0; mt < 4; ++mt) {
        #pragma unroll
        for (int kt = 0; kt < 2; ++kt) {
            Xf[mt][kt] = load_cvt8(xrow + (16 * mt + lr) * 64 + 32 * kt + 8 * hi);
        }
    }

    // ---- Stage 1: U(k,q) = sum_l X(k,l) * B(q,l); write U to LDS k-contiguous.
    // C/D layout: lane's r-th value is U[16mt + 4hi + r][16nt + lr].
    // Byte offset = q*128 + k*2, XOR-swizzled by ((q&7)<<4). ----
    #pragma unroll
    for (int mt = 0; mt < 4; ++mt) {
        #pragma unroll
        for (int nt = 0; nt < 4; ++nt) {
            f32x4 u = {0.f, 0.f, 0.f, 0.f};
            u = MFMA16(Xf[mt][0], Bf[nt][0], u);
            u = MFMA16(Xf[mt][1], Bf[nt][1], u);
            const int q   = 16 * nt + lr;
            const int k0  = 16 * mt + 4 * hi;
            const int off = (q * 128 + k0 * 2) ^ ((q & 7) << 4);
            bf16x4 v;
            v[0] = (__bf16)u[0];
            v[1] = (__bf16)u[1];
            v[2] = (__bf16)u[2];
            v[3] = (__bf16)u[3];
            *reinterpret_cast<bf16x4*>(ubase + off) = v;
        }
    }

    // Make this wave's LDS writes visible to its reads.
    asm volatile("s_waitcnt lgkmcnt(0)" ::: "memory");

    // ---- U^T fragments (stage-2 A-operand): lane holds U[32kt+8hi+j][16qt+lr],
    // i.e. Aop[row=q=lr][K=k] = U^T. One ds_read_b128 each, conflict-free. ----
    bf16x8 Uf[2][4];
    #pragma unroll
    for (int kt = 0; kt < 2; ++kt) {
        #pragma unroll
        for (int qt = 0; qt < 4; ++qt) {
            const int q   = 16 * qt + lr;
            const int k0  = 32 * kt + 8 * hi;
            const int off = (q * 128 + k0 * 2) ^ ((q & 7) << 4);
            Uf[kt][qt] = *reinterpret_cast<const bf16x8*>(ubase + off);
        }
    }

    // ---- Stage 2 (transposed): D[q][p] = sum_k U^T[q][k] * A^T[k][p].
    // Aop = Uf (row=q), Bop = Af (col=p). Lane's r-th value:
    // D[16qt + 4hi + r][16pt + lr] = out[p=16pt+lr][q=16qt+4hi+r]
    // -> 4 consecutive q values -> float4 non-temporal store. ----
    float* orow = out + (size_t)m * 4096;
    #pragma unroll
    for (int pt = 0; pt < 4; ++pt) {
        #pragma unroll
        for (int qt = 0; qt < 4; ++qt) {
            f32x4 acc = {0.f, 0.f, 0.f, 0.f};
            acc = MFMA16(Uf[0][qt], Af[pt][0], acc);
            acc = MFMA16(Uf[1][qt], Af[pt][1], acc);
            const int p   = 16 * pt + lr;
            const int q0  = 16 * qt + 4 * hi;
            const int col = p * 64 + q0;
            const f32x4 bv = *reinterpret_cast<const f32x4*>(bias + col);
            f32x4 o;
            o[0] = acc[0] + bv[0];
            o[1] = acc[1] + bv[1];
            o[2] = acc[2] + bv[2];
            o[3] = acc[3] + bv[3];
            __builtin_nontemporal_store(o, reinterpret_cast<f32x4*>(orow + col));
        }
    }
}

extern "C" void kernel_launch(void* const* d_in, const int* in_sizes, int n_in,
                              void* d_out, int out_size, void* d_ws, size_t ws_size,
                              hipStream_t stream) {
    const float* x    = (const float*)d_in[0];
    const float* A    = (const float*)d_in[1];
    const float* B    = (const float*)d_in[2];
    const float* bias = (const float*)d_in[3];
    float* out        = (float*)d_out;

    // 2048 blocks x 4 waves = 8192 waves, one output row each.
    kron_linear_kernel<<<dim3(2048), dim3(256), 0, stream>>>(x, A, B, bias, out);
}

// Round 6
// 76.918 us; speedup vs baseline: 1.0035x; 1.0027x over previous
//
#include <hip/hip_runtime.h>
#include <hip/hip_bf16.h>

// out[m, p*64+q] = sum_{k,l} x[m, k*64+l] * A[p,k] * B[q,l] + bias[p*64+q]
// Per row m: U = X * B^T (contract l), then out_tile^T = U^T * A^T (contract k)
// so each lane's 4 accumulator values are CONSECUTIVE q -> float4 stores.
// One wave per row, 8192 waves total. MFMA 16x16x32 bf16, fp32 accumulate.
// Round 3: non-temporal output stores so the 128 MiB write stream does not
// evict x from the 256 MiB Infinity Cache between graph replays.

typedef __bf16 bf16x8 __attribute__((ext_vector_type(8)));
typedef __bf16 bf16x4 __attribute__((ext_vector_type(4)));
typedef float  f32x4  __attribute__((ext_vector_type(4)));

#define MFMA16(Aop, Bop, C) __builtin_amdgcn_mfma_f32_16x16x32_bf16(Aop, Bop, C, 0, 0, 0)

__device__ __forceinline__ bf16x8 load_cvt8(const float* __restrict__ p) {
    const float4 a = *reinterpret_cast<const float4*>(p);
    const float4 b = *reinterpret_cast<const float4*>(p + 4);
    bf16x8 r;
    r[0] = (__bf16)a.x; r[1] = (__bf16)a.y; r[2] = (__bf16)a.z; r[3] = (__bf16)a.w;
    r[4] = (__bf16)b.x; r[5] = (__bf16)b.y; r[6] = (__bf16)b.z; r[7] = (__bf16)b.w;
    return r;
}

__global__ __launch_bounds__(256, 4)
void kron_linear_kernel(const float* __restrict__ x,
                        const float* __restrict__ A,
                        const float* __restrict__ B,
                        const float* __restrict__ bias,
                        float* __restrict__ out) {
    // Per-wave 64x64 bf16 U buffer, stored transposed (k-contiguous), XOR-swizzled.
    __shared__ __align__(16) __bf16 Ulds[4][64 * 64];

    const int lane = threadIdx.x & 63;
    const int wv   = threadIdx.x >> 6;    // wave in block, 0..3
    const int lr   = lane & 15;           // lane % 16
    const int hi   = lane >> 4;           // 0..3 (K-chunk group)
    const int m    = blockIdx.x * 4 + wv; // row id, 0..8191

    char* ubase = (char*)(&Ulds[wv][0]);
    const float* xrow = x + (size_t)m * 4096;

    // ---- Constant fragments ----
    // Af[t][kt]: lane holds A[16t+lr][32kt + 8hi + j]   (used as B-operand = A^T)
    // Bf[t][kt]: lane holds B[16t+lr][32kt + 8hi + j]   (stage-1 B-operand)
    bf16x8 Af[4][2], Bf[4][2];
    #pragma unroll
    for (int t = 0; t < 4; ++t) {
        #pragma unroll
        for (int kt = 0; kt < 2; ++kt) {
            const int row = 16 * t + lr;
            const int c0  = 32 * kt + 8 * hi;
            Af[t][kt] = load_cvt8(A + row * 64 + c0);
            Bf[t][kt] = load_cvt8(B + row * 64 + c0);
        }
    }

    // ---- X fragments: stage-1 A-operand. lane holds X[16mt+lr][32kt+8hi+j] ----
    bf16x8 Xf[4][2];
    #pragma unroll
    for (int mt = 0; mt < 4; ++mt) {
        #pragma unroll
        for (int kt = 0; kt < 2; ++kt) {
            Xf[mt][kt] = load_cvt8(xrow + (16 * mt + lr) * 64 + 32 * kt + 8 * hi);
        }
    }

    // ---- Stage 1: U(k,q) = sum_l X(k,l) * B(q,l); write U to LDS k-contiguous.
    // C/D layout: lane's r-th value is U[16mt + 4hi + r][16nt + lr].
    // Byte offset = q*128 + k*2, XOR-swizzled by ((q&7)<<4). ----
    #pragma unroll
    for (int mt = 0; mt < 4; ++mt) {
        #pragma unroll
        for (int nt = 0; nt < 4; ++nt) {
            f32x4 u = {0.f, 0.f, 0.f, 0.f};
            u = MFMA16(Xf[mt][0], Bf[nt][0], u);
            u = MFMA16(Xf[mt][1], Bf[nt][1], u);
            const int q   = 16 * nt + lr;
            const int k0  = 16 * mt + 4 * hi;
            const int off = (q * 128 + k0 * 2) ^ ((q & 7) << 4);
            bf16x4 v;
            v[0] = (__bf16)u[0];
            v[1] = (__bf16)u[1];
            v[2] = (__bf16)u[2];
            v[3] = (__bf16)u[3];
            *reinterpret_cast<bf16x4*>(ubase + off) = v;
        }
    }

    // Make this wave's LDS writes visible to its reads.
    asm volatile("s_waitcnt lgkmcnt(0)" ::: "memory");

    // ---- U^T fragments (stage-2 A-operand): lane holds U[32kt+8hi+j][16qt+lr],
    // i.e. Aop[row=q=lr][K=k] = U^T. One ds_read_b128 each, conflict-free. ----
    bf16x8 Uf[2][4];
    #pragma unroll
    for (int kt = 0; kt < 2; ++kt) {
        #pragma unroll
        for (int qt = 0; qt < 4; ++qt) {
            const int q   = 16 * qt + lr;
            const int k0  = 32 * kt + 8 * hi;
            const int off = (q * 128 + k0 * 2) ^ ((q & 7) << 4);
            Uf[kt][qt] = *reinterpret_cast<const bf16x8*>(ubase + off);
        }
    }

    // ---- Stage 2 (transposed): D[q][p] = sum_k U^T[q][k] * A^T[k][p].
    // Aop = Uf (row=q), Bop = Af (col=p). Lane's r-th value:
    // D[16qt + 4hi + r][16pt + lr] = out[p=16pt+lr][q=16qt+4hi+r]
    // -> 4 consecutive q values -> float4 non-temporal store. ----
    float* orow = out + (size_t)m * 4096;
    #pragma unroll
    for (int pt = 0; pt < 4; ++pt) {
        #pragma unroll
        for (int qt = 0; qt < 4; ++qt) {
            f32x4 acc = {0.f, 0.f, 0.f, 0.f};
            acc = MFMA16(Uf[0][qt], Af[pt][0], acc);
            acc = MFMA16(Uf[1][qt], Af[pt][1], acc);
            const int p   = 16 * pt + lr;
            const int q0  = 16 * qt + 4 * hi;
            const int col = p * 64 + q0;
            const f32x4 bv = *reinterpret_cast<const f32x4*>(bias + col);
            f32x4 o;
            o[0] = acc[0] + bv[0];
            o[1] = acc[1] + bv[1];
            o[2] = acc[2] + bv[2];
            o[3] = acc[3] + bv[3];
            __builtin_nontemporal_store(o, reinterpret_cast<f32x4*>(orow + col));
        }
    }
}

extern "C" void kernel_launch(void* const* d_in, const int* in_sizes, int n_in,
                              void* d_out, int out_size, void* d_ws, size_t ws_size,
                              hipStream_t stream) {
    const float* x    = (const float*)d_in[0];
    const float* A    = (const float*)d_in[1];
    const float* B    = (const float*)d_in[2];
    const float* bias = (const float*)d_in[3];
    float* out        = (float*)d_out;

    // 2048 blocks x 4 waves = 8192 waves, one output row each.
    kron_linear_kernel<<<dim3(2048), dim3(256), 0, stream>>>(x, A, B, bias, out);
}

// Round 7
// 70.001 us; speedup vs baseline: 1.1027x; 1.0988x over previous
//
#include <hip/hip_runtime.h>
#include <hip/hip_bf16.h>

// out[m, p*64+q] = sum_{k,l} x[m, k*64+l] * A[p,k] * B[q,l] + bias[p*64+q]
// Per row m: U = X * B^T (contract l), then out_tile^T = U^T * A^T (contract k).
// One wave per row, 8192 waves. MFMA 16x16x32 bf16, fp32 accumulate.
// Round 7: stage the 64x64 f32 output tile through LDS (reusing the dead U
// buffer, two 32x64 halves) and emit fully-linear NT stores: each store
// instruction writes 1 KB contiguous (8 complete 128B lines) instead of
// 16 scattered 64B chunks -> kills the 1.39x write amplification and the
// store-drain that parks waves at endpgm.

typedef __bf16 bf16x8 __attribute__((ext_vector_type(8)));
typedef __bf16 bf16x4 __attribute__((ext_vector_type(4)));
typedef float  f32x4  __attribute__((ext_vector_type(4)));

#define MFMA16(Aop, Bop, C) __builtin_amdgcn_mfma_f32_16x16x32_bf16(Aop, Bop, C, 0, 0, 0)

__device__ __forceinline__ bf16x8 load_cvt8(const float* __restrict__ p) {
    const float4 a = *reinterpret_cast<const float4*>(p);
    const float4 b = *reinterpret_cast<const float4*>(p + 4);
    bf16x8 r;
    r[0] = (__bf16)a.x; r[1] = (__bf16)a.y; r[2] = (__bf16)a.z; r[3] = (__bf16)a.w;
    r[4] = (__bf16)b.x; r[5] = (__bf16)b.y; r[6] = (__bf16)b.z; r[7] = (__bf16)b.w;
    return r;
}

__global__ __launch_bounds__(256, 4)
void kron_linear_kernel(const float* __restrict__ x,
                        const float* __restrict__ A,
                        const float* __restrict__ B,
                        const float* __restrict__ bias,
                        float* __restrict__ out) {
    // Per-wave 8 KB buffer: first holds U (64x64 bf16, k-contiguous, swizzled),
    // then is reused as the f32 [32][64] output staging tile (two halves).
    __shared__ __align__(16) char Ulds[4][8192];

    const int lane = threadIdx.x & 63;
    const int wv   = threadIdx.x >> 6;    // wave in block, 0..3
    const int lr   = lane & 15;           // lane % 16
    const int hi   = lane >> 4;           // 0..3
    const int m    = blockIdx.x * 4 + wv; // row id, 0..8191

    char* ubase = &Ulds[wv][0];
    const float* xrow = x + (size_t)m * 4096;

    // ---- Constant fragments ----
    // Af[t][kt]: lane holds A[16t+lr][32kt + 8hi + j]   (stage-2 B-operand = A^T)
    // Bf[t][kt]: lane holds B[16t+lr][32kt + 8hi + j]   (stage-1 B-operand)
    bf16x8 Af[4][2], Bf[4][2];
    #pragma unroll
    for (int t = 0; t < 4; ++t) {
        #pragma unroll
        for (int kt = 0; kt < 2; ++kt) {
            const int row = 16 * t + lr;
            const int c0  = 32 * kt + 8 * hi;
            Af[t][kt] = load_cvt8(A + row * 64 + c0);
            Bf[t][kt] = load_cvt8(B + row * 64 + c0);
        }
    }

    // ---- X fragments: stage-1 A-operand. lane holds X[16mt+lr][32kt+8hi+j] ----
    bf16x8 Xf[4][2];
    #pragma unroll
    for (int mt = 0; mt < 4; ++mt) {
        #pragma unroll
        for (int kt = 0; kt < 2; ++kt) {
            Xf[mt][kt] = load_cvt8(xrow + (16 * mt + lr) * 64 + 32 * kt + 8 * hi);
        }
    }

    // ---- Stage 1: U(k,q) = sum_l X(k,l) * B(q,l); write U to LDS k-contiguous.
    // C/D layout: lane's r-th value is U[16mt + 4hi + r][16nt + lr].
    // Byte offset = q*128 + k*2, XOR-swizzled by ((q&7)<<4). ----
    #pragma unroll
    for (int mt = 0; mt < 4; ++mt) {
        #pragma unroll
        for (int nt = 0; nt < 4; ++nt) {
            f32x4 u = {0.f, 0.f, 0.f, 0.f};
            u = MFMA16(Xf[mt][0], Bf[nt][0], u);
            u = MFMA16(Xf[mt][1], Bf[nt][1], u);
            const int q   = 16 * nt + lr;
            const int k0  = 16 * mt + 4 * hi;
            const int off = (q * 128 + k0 * 2) ^ ((q & 7) << 4);
            bf16x4 v;
            v[0] = (__bf16)u[0];
            v[1] = (__bf16)u[1];
            v[2] = (__bf16)u[2];
            v[3] = (__bf16)u[3];
            *reinterpret_cast<bf16x4*>(ubase + off) = v;
        }
    }

    asm volatile("s_waitcnt lgkmcnt(0)" ::: "memory");

    // ---- U^T fragments (stage-2 A-operand): lane holds U[32kt+8hi+j][16qt+lr].
    // One ds_read_b128 each. After this (and the wait), the buffer is dead. ----
    bf16x8 Uf[2][4];
    #pragma unroll
    for (int kt = 0; kt < 2; ++kt) {
        #pragma unroll
        for (int qt = 0; qt < 4; ++qt) {
            const int q   = 16 * qt + lr;
            const int k0  = 32 * kt + 8 * hi;
            const int off = (q * 128 + k0 * 2) ^ ((q & 7) << 4);
            Uf[kt][qt] = *reinterpret_cast<const bf16x8*>(ubase + off);
        }
    }

    // Uf data must be in registers before the out-stage overwrites the buffer.
    asm volatile("s_waitcnt lgkmcnt(0)" ::: "memory");

    // ---- Stage 2 (transposed): D[q][p] = sum_k U^T[q][k] * A^T[k][p].
    // Lane's r-th acc value is out[p=16pt+lr][q=16qt+4hi+r]. Stage each
    // 32-row half-tile (8 KB f32) into LDS, then stream it out linearly:
    // one instruction = 64 lanes x 16B = 1 KB contiguous. ----
    float* orow = out + (size_t)m * 4096;
    #pragma unroll
    for (int h = 0; h < 2; ++h) {
        #pragma unroll
        for (int ptl = 0; ptl < 2; ++ptl) {
            const int pt = 2 * h + ptl;
            #pragma unroll
            for (int qt = 0; qt < 4; ++qt) {
                f32x4 acc = {0.f, 0.f, 0.f, 0.f};
                acc = MFMA16(Uf[0][qt], Af[pt][0], acc);
                acc = MFMA16(Uf[1][qt], Af[pt][1], acc);
                // Stage at (pp, q0): byte off = pp*256 + q0*4, swizzled.
                const int pp  = 16 * ptl + lr;       // row within half-tile
                const int q0  = 16 * qt + 4 * hi;
                const int off = (pp * 256 + q0 * 4) ^ ((pp & 7) << 4);
                *reinterpret_cast<f32x4*>(ubase + off) = acc;
            }
        }
        asm volatile("s_waitcnt lgkmcnt(0)" ::: "memory");

        // Linear read-back: lane reads floats [i*256 + 4*lane .. +3], i.e.
        // row pp = 4i+hi, cols 4*lr.. of the half-tile. Add bias, NT store.
        #pragma unroll
        for (int i = 0; i < 8; ++i) {
            const int pp  = 4 * i + hi;
            const int off = (i * 1024 + lane * 16) ^ ((pp & 7) << 4);
            const f32x4 v = *reinterpret_cast<const f32x4*>(ubase + off);
            const int col = 2048 * h + i * 256 + lane * 4;
            const f32x4 bv = *reinterpret_cast<const f32x4*>(bias + col);
            f32x4 o;
            o[0] = v[0] + bv[0];
            o[1] = v[1] + bv[1];
            o[2] = v[2] + bv[2];
            o[3] = v[3] + bv[3];
            __builtin_nontemporal_store(o, reinterpret_cast<f32x4*>(orow + col));
        }
        // Half-tile reads must complete before the next half overwrites LDS.
        asm volatile("s_waitcnt lgkmcnt(0)" ::: "memory");
    }
}

extern "C" void kernel_launch(void* const* d_in, const int* in_sizes, int n_in,
                              void* d_out, int out_size, void* d_ws, size_t ws_size,
                              hipStream_t stream) {
    const float* x    = (const float*)d_in[0];
    const float* A    = (const float*)d_in[1];
    const float* B    = (const float*)d_in[2];
    const float* bias = (const float*)d_in[3];
    float* out        = (float*)d_out;

    // 2048 blocks x 4 waves = 8192 waves, one output row each.
    kron_linear_kernel<<<dim3(2048), dim3(256), 0, stream>>>(x, A, B, bias, out);
}